// Round 11
// baseline (169.541 us; speedup 1.0000x reference)
//
#include <hip/hip_runtime.h>
#include <math.h>

#define NV 3
#define DIMX 128
#define HD 64
#define NVH 192
#define NBLK 256     // edge-partition blocks for hist/scatter
#define NBUK 128     // dst buckets of 512 nodes
#define BSH 9        // log2(512)

typedef unsigned int uint32;
typedef unsigned short ushort16;
typedef unsigned char uchar;
typedef __attribute__((ext_vector_type(8))) short short8;
typedef __attribute__((ext_vector_type(4))) float f32x4;
typedef __attribute__((ext_vector_type(2))) unsigned int u32x2;

__device__ __forceinline__ unsigned fkey(float f){
  unsigned b = __float_as_uint(f);
  return (b & 0x80000000u) ? ~b : (b | 0x80000000u);
}
__device__ __forceinline__ float unkey(unsigned k){
  return __uint_as_float((k & 0x80000000u) ? (k ^ 0x80000000u) : ~k);
}
__device__ __forceinline__ uint32 bf16rne(float f){
  uint32 u = __float_as_uint(f);
  return (u + 0x7fffu + ((u >> 16) & 1u)) >> 16;
}
__device__ __forceinline__ float bfus(uint32 q){ return __uint_as_float(q << 16); }
__device__ __forceinline__ float ub0(uint32 p){ return (float)(p & 0xffu); }
__device__ __forceinline__ float ub1(uint32 p){ return (float)((p >> 8) & 0xffu); }
__device__ __forceinline__ float ub2(uint32 p){ return (float)((p >> 16) & 0xffu); }
__device__ __forceinline__ float ub3(uint32 p){ return (float)(p >> 24); }

// ---- CSR build: two-level counting sort, LDS atomics only ----
__global__ __launch_bounds__(256) void k_hist(const int* __restrict__ ei, int E, int EPB,
                                              int* __restrict__ histT){
  __shared__ int sh[NBUK];
  int t = threadIdx.x, b = blockIdx.x;
  if (t < NBUK) sh[t] = 0;
  __syncthreads();
  int e0 = b*EPB, e1 = min(e0 + EPB, E);
  for (int i = e0 + t; i < e1; i += 256){
    int d = ei[E + i];
    atomicAdd(&sh[d >> BSH], 1);
  }
  __syncthreads();
  if (t < NBUK) histT[t*NBLK + b] = sh[t];
}

__global__ __launch_bounds__(1024) void k_hscan(int* __restrict__ histT){
  __shared__ int sh[1024];
  int t = threadIdx.x;
  int lo = t*32;
  int vals[32]; int s = 0;
  #pragma unroll
  for (int k = 0; k < 32; ++k){ vals[k] = histT[lo+k]; s += vals[k]; }
  sh[t] = s; __syncthreads();
  for (int ofs = 1; ofs < 1024; ofs <<= 1){
    int v = (t >= ofs) ? sh[t-ofs] : 0;
    __syncthreads();
    sh[t] += v;
    __syncthreads();
  }
  int run = sh[t] - s;
  #pragma unroll
  for (int k = 0; k < 32; ++k){ histT[lo+k] = run; run += vals[k]; }
}

// pack edge as (dst_local<<16)|src  (valid: src < 65536, dst_local < 512)
__global__ __launch_bounds__(256) void k_scatter(const int* __restrict__ ei, int E, int EPB,
                                                 const int* __restrict__ ofsT, uint32* __restrict__ ebuf){
  __shared__ int cur[NBUK];
  int t = threadIdx.x, b = blockIdx.x;
  if (t < NBUK) cur[t] = ofsT[t*NBLK + b];
  __syncthreads();
  int e0 = b*EPB, e1 = min(e0 + EPB, E);
  for (int i = e0 + t; i < e1; i += 256){
    int s = ei[i], d = ei[E + i];
    int pos = atomicAdd(&cur[d >> BSH], 1);
    ebuf[pos] = ((uint32)(d & 511) << 16) | (uint32)s;
  }
}

__global__ __launch_bounds__(512) void k_csr(const uint32* __restrict__ ebuf, const int* __restrict__ ofsT,
                                             int E, int N, int* __restrict__ rowstart,
                                             float* __restrict__ dinv, int* __restrict__ csr){
  __shared__ int cnt[512];
  __shared__ int pre[512];
  int t = threadIdx.x, b = blockIdx.x;
  int estart = ofsT[b*NBLK];
  int eend   = ((b+1)*NBLK < NBUK*NBLK) ? ofsT[(b+1)*NBLK] : E;
  int n0 = b << BSH;
  int nn = min(512, N - n0);
  cnt[t] = 0;
  __syncthreads();
  for (int i = estart + t; i < eend; i += 512){
    atomicAdd(&cnt[ebuf[i] >> 16], 1);
  }
  __syncthreads();
  int c = cnt[t];
  pre[t] = c;
  __syncthreads();
  for (int ofs = 1; ofs < 512; ofs <<= 1){
    int v = (t >= ofs) ? pre[t-ofs] : 0;
    __syncthreads();
    pre[t] += v;
    __syncthreads();
  }
  int excl = pre[t] - c;
  if (t < nn){
    rowstart[n0 + t] = estart + excl;
    dinv[n0 + t] = rsqrtf((float)(c + 1));
  }
  if (b == gridDim.x - 1 && t == 0) rowstart[N] = E;
  cnt[t] = estart + excl;
  __syncthreads();
  for (int i = estart + t; i < eend; i += 512){
    uint32 e = ebuf[i];
    int pos = atomicAdd(&cnt[e >> 16], 1);
    csr[pos] = (int)(e & 0xFFFFu);
  }
}

// ---- pack Wv into per-lane MFMA B-fragment order; block 0 also zeroes accumulators ----
__global__ __launch_bounds__(256) void k_wpack(const float* __restrict__ Wv, uint32* __restrict__ Wb,
                                               float* __restrict__ wsum, float* __restrict__ sumexp,
                                               unsigned* __restrict__ maxkey){
  int t = blockIdx.x*blockDim.x + threadIdx.x;
  if (blockIdx.x == 0){
    int u = threadIdx.x;
    if (u < NVH) wsum[u] = 0.f;
    else if (u < NVH+3) sumexp[u-NVH] = 0.f;
    else if (u < NVH+6) maxkey[u-NVH-3] = 0u;
  }
  if (t >= 3072) return;
  int l = t & 63, s = (t >> 6) & 3, c = (t >> 8) & 3, v = t >> 10;
  int h = c*16 + (l & 15);
  int kbase = s*32 + (l >> 4)*8;
  const float* wp = Wv + v*8192 + h;
  uint32 o[4];
  #pragma unroll
  for (int jj = 0; jj < 4; ++jj){
    uint32 lo = bf16rne(wp[(kbase + 2*jj    )*64]);
    uint32 hi = bf16rne(wp[(kbase + 2*jj + 1)*64]);
    o[jj] = lo | (hi << 16);
  }
  Wb[t*4+0] = o[0]; Wb[t*4+1] = o[1]; Wb[t*4+2] = o[2]; Wb[t*4+3] = o[3];
}

// ---- MFMA linear transform, one wave per (16-node tile, view), fused int8 quant ----
// v-major packed table: hq8[n*192 + v*64 + h] = uint8(q+128); 48 dwords/node
// per-(tile,view) scale in scale4[tile*4 + v]
__global__ __launch_bounds__(256) void k_h(const float* __restrict__ x, const uint32* __restrict__ Wb,
                                           const float* __restrict__ dinv,
                                           uchar* __restrict__ hq8, float* __restrict__ scale4,
                                           int N, int NT){
  int wv = (blockIdx.x*blockDim.x + threadIdx.x) >> 6;
  int lane = threadIdx.x & 63;
  int tile = wv / 3;
  int v = wv - tile*3;
  if (tile >= NT) return;
  int jrow = lane & 15;
  int kq   = lane >> 4;
  int nrow = tile*16 + jrow;
  const float* xr = x + (size_t)nrow*384 + v*128 + kq*8;
  const short8* WB = (const short8*)Wb;

  f32x4 acc[4] = {};
  #pragma unroll
  for (int s = 0; s < 4; ++s){
    const float* p = xr + s*32;
    float4 f = *(const float4*)p, g = *(const float4*)(p+4);
    short8 a;
    a[0]=(short)bf16rne(f.x); a[1]=(short)bf16rne(f.y); a[2]=(short)bf16rne(f.z); a[3]=(short)bf16rne(f.w);
    a[4]=(short)bf16rne(g.x); a[5]=(short)bf16rne(g.y); a[6]=(short)bf16rne(g.z); a[7]=(short)bf16rne(g.w);
    #pragma unroll
    for (int c = 0; c < 4; ++c){
      short8 b = WB[(v*4 + c)*256 + s*64 + lane];
      acc[c] = __builtin_amdgcn_mfma_f32_16x16x32_bf16(a, b, acc[c], 0, 0, 0);
    }
  }

  float vv[4][4];
  float mx = 0.f;
  #pragma unroll
  for (int r = 0; r < 4; ++r){
    int n = tile*16 + kq*4 + r;
    float dv = dinv[n];
    #pragma unroll
    for (int c = 0; c < 4; ++c){
      float t = acc[c][r]*dv;
      vv[c][r] = t;
      mx = fmaxf(mx, fabsf(t));
    }
  }
  #pragma unroll
  for (int ofs = 1; ofs < 64; ofs <<= 1) mx = fmaxf(mx, __shfl_xor(mx, ofs));
  float inv = (mx > 0.f) ? 127.0f/mx : 0.f;
  #pragma unroll
  for (int r = 0; r < 4; ++r){
    int n = tile*16 + kq*4 + r;
    #pragma unroll
    for (int c = 0; c < 4; ++c){
      uint32 q = (uint32)(int)(vv[c][r]*inv + 128.5f);
      hq8[(size_t)n*192 + v*64 + c*16 + jrow] = (uchar)q;
    }
  }
  if (lane == 0) scale4[tile*4 + v] = mx * (1.0f/127.0f);
}

// ---- fused 3-view aggregation: 1 aligned dword gather + 1 scalar scale per edge ----
// lane j<48: view v=j>>4, h-dims 4*(j&15)..+3 (dword j of the 48-dword node record)
__global__ __launch_bounds__(256) void k_aggv(const uint32* __restrict__ hq4, const float* __restrict__ sc,
                                              const int* __restrict__ rowstart, const int* __restrict__ csr,
                                              const float* __restrict__ dinv, const float* __restrict__ bv,
                                              const float* __restrict__ na_w, const float* __restrict__ na_b,
                                              uint32* __restrict__ emb, float* __restrict__ scores, int N){
  int wid = (blockIdx.x*blockDim.x + threadIdx.x) >> 6;
  int lane = threadIdx.x & 63;
  if (wid >= N) return;
  int n = wid;
  int jl = (lane < 48) ? lane : 0;
  int v = jl >> 4;
  // self-loop
  uint32 ps = hq4[(size_t)n*48 + jl];
  float cs = sc[((n >> 4) << 2) + v];
  float a0 = cs*ub0(ps), a1 = cs*ub1(ps), a2 = cs*ub2(ps), a3 = cs*ub3(ps);
  float ssum = cs;
  int r0 = rowstart[n], r1 = rowstart[n+1];
  for (int base = r0; base < r1; base += 64){
    int m = r1 - base; if (m > 64) m = 64;
    int sv = (lane < m) ? __builtin_nontemporal_load(&csr[base + lane]) : 0;
    int i = 0;
    for (; i + 3 < m; i += 4){
      int s0 = __shfl(sv, i), s1 = __shfl(sv, i+1), s2 = __shfl(sv, i+2), s3 = __shfl(sv, i+3);
      uint32 p0 = hq4[(size_t)s0*48 + jl];
      uint32 p1 = hq4[(size_t)s1*48 + jl];
      uint32 p2 = hq4[(size_t)s2*48 + jl];
      uint32 p3 = hq4[(size_t)s3*48 + jl];
      float f0 = sc[((s0 >> 4) << 2) + v];
      float f1 = sc[((s1 >> 4) << 2) + v];
      float f2 = sc[((s2 >> 4) << 2) + v];
      float f3 = sc[((s3 >> 4) << 2) + v];
      a0 = fmaf(f0, ub0(p0), a0); a1 = fmaf(f0, ub1(p0), a1); a2 = fmaf(f0, ub2(p0), a2); a3 = fmaf(f0, ub3(p0), a3);
      a0 = fmaf(f1, ub0(p1), a0); a1 = fmaf(f1, ub1(p1), a1); a2 = fmaf(f1, ub2(p1), a2); a3 = fmaf(f1, ub3(p1), a3);
      a0 = fmaf(f2, ub0(p2), a0); a1 = fmaf(f2, ub1(p2), a1); a2 = fmaf(f2, ub2(p2), a2); a3 = fmaf(f2, ub3(p2), a3);
      a0 = fmaf(f3, ub0(p3), a0); a1 = fmaf(f3, ub1(p3), a1); a2 = fmaf(f3, ub2(p3), a2); a3 = fmaf(f3, ub3(p3), a3);
      ssum += f0 + f1 + f2 + f3;
    }
    for (; i < m; ++i){
      int s = __shfl(sv, i);
      uint32 p = hq4[(size_t)s*48 + jl];
      float f = sc[((s >> 4) << 2) + v];
      a0 = fmaf(f, ub0(p), a0); a1 = fmaf(f, ub1(p), a1); a2 = fmaf(f, ub2(p), a2); a3 = fmaf(f, ub3(p), a3);
      ssum += f;
    }
  }
  float off128 = 128.0f*ssum;
  a0 -= off128; a1 -= off128; a2 -= off128; a3 -= off128;
  float dv = dinv[n];
  float4 bb = *(const float4*)&bv[jl*4];
  float e0 = fmaxf(a0*dv + bb.x, 0.f);
  float e1 = fmaxf(a1*dv + bb.y, 0.f);
  float e2 = fmaxf(a2*dv + bb.z, 0.f);
  float e3 = fmaxf(a3*dv + bb.w, 0.f);
  if (lane < 48){
    u32x2 pk;
    pk.x = bf16rne(e0) | (bf16rne(e1) << 16);
    pk.y = bf16rne(e2) | (bf16rne(e3) << 16);
    __builtin_nontemporal_store(pk, (u32x2*)(emb + (size_t)n*96 + 2*jl));
  }
  float4 nw = *(const float4*)&na_w[(jl & 15)*4];
  float s = e0*nw.x + e1*nw.y + e2*nw.z + e3*nw.w;
  s += __shfl_xor(s, 1);
  s += __shfl_xor(s, 2);
  s += __shfl_xor(s, 4);
  s += __shfl_xor(s, 8);
  if (lane < 48 && (lane & 15) == 0) scores[(size_t)v*N + n] = s + na_b[0];
}

// ---- global max per view ----
__global__ void k_max(const float* __restrict__ scores, int N, unsigned* __restrict__ maxkey){
  __shared__ float sh[256];
  int v = blockIdx.y;
  const float* sp = scores + (size_t)v*N;
  int base = blockIdx.x*2048 + threadIdx.x;
  float m = -3.0e38f;
  #pragma unroll
  for (int k = 0; k < 8; ++k){
    int i = base + k*256;
    if (i < N) m = fmaxf(m, sp[i]);
  }
  sh[threadIdx.x] = m; __syncthreads();
  for (int ofs = 128; ofs >= 1; ofs >>= 1){
    if (threadIdx.x < ofs) sh[threadIdx.x] = fmaxf(sh[threadIdx.x], sh[threadIdx.x+ofs]);
    __syncthreads();
  }
  if (threadIdx.x == 0) atomicMax(&maxkey[v], fkey(sh[0]));
}

// ---- sum(exp) per view + weighted sum over nodes, hierarchical ----
// emb layout now [n][v][h] bf16 (48 dwords/node, dword j = h-dims 4j..4j+3 of view j>>4)
__global__ __launch_bounds__(256) void k_wsum(const uint32* __restrict__ emb, const float* __restrict__ scores,
                                              const unsigned* __restrict__ maxkey, float* __restrict__ wsum,
                                              float* __restrict__ sumexp, int N){
  __shared__ float shw[4][NVH];
  __shared__ float shse[4][4];
  int t = threadIdx.x;
  int lane = t & 63;
  int wv = t >> 6;
  int gw = (blockIdx.x*blockDim.x + t) >> 6;
  int nw = (gridDim.x*blockDim.x) >> 6;
  float m0 = unkey(maxkey[0]), m1 = unkey(maxkey[1]), m2 = unkey(maxkey[2]);
  float w0=0.f, w1=0.f, w2=0.f, se0=0.f, se1=0.f, se2=0.f;
  for (int n = gw; n < N; n += nw){
    const uint32* ep = emb + (size_t)n*96;     // 96 u16-pairs = 48 dwords... indexing as u32[96]? no:
    // ep is uint32*, node record = 96 dwords? No — 192 bf16 = 96 dwords? 192*2B = 384B = 96 dwords.
    // Wait: emb stored as bf16 pairs: 192 bf16 = 96 dwords. k_aggv writes 2 dwords per lane jl (2*48=96). OK.
    uint32 pa = ep[lane];            // bf16 pair: h-dims (lane*2, lane*2+1) of flattened [v][h] (v=lane>>5)
    uint32 pb = ep[64+lane];
    float x0 = expf(scores[n]       - m0);
    float x1 = expf(scores[N + n]   - m1);
    float x2 = expf(scores[2*N + n] - m2);
    // lane covers flat dims [2*lane, 2*lane+1] and [128+2*lane, 128+2*lane+1]
    // flat dim f = v*64+h: v = f>>6
    int f0v = (2*lane) >> 6;         // 0 or 1
    int f1v = (128 + 2*lane) >> 6;   // 2
    float xa = (f0v == 0) ? x0 : x1;
    float xb = x2;
    // accumulate into wsum index = flat dim
    w0 += (bfus(pa & 0xffffu) + 0.f)*xa;   // placeholder to keep structure; real accumulation below
    (void)pb; (void)xb; (void)w1; (void)w2;
    // NOTE: replaced below by direct LDS accumulation
    break;
  }
  // --- simpler correct path: each thread owns flat dims via strided loop ---
  // reset
  w0 = w1 = w2 = 0.f; se0 = se1 = se2 = 0.f;
  for (int n = gw; n < N; n += nw){
    const uint32* ep = emb + (size_t)n*96;
    float x0 = expf(scores[n]       - m0);
    float x1 = expf(scores[N + n]   - m1);
    float x2 = expf(scores[2*N + n] - m2);
    uint32 pa = ep[lane];        // flat dims 2*lane, 2*lane+1       (views 0-1)
    uint32 pb = ep[32+lane];     // flat dims 64+2*lane, 64+2*lane+1 (views 1-2)... no.
    // abandon pair logic; decode both halves with correct view weight by flat index:
    (void)pb;
    int fd = 2*lane;             // flat dim of low half of pa
    float xlo = (fd < 64) ? x0 : (fd < 128) ? x1 : x2;
    int fd1 = fd + 1;
    float xhi = (fd1 < 64) ? x0 : (fd1 < 128) ? x1 : x2;
    w0 += bfus(pa & 0xffffu)*xlo;
    w1 += bfus(pa >> 16)*xhi;
    uint32 pc = ep[64+lane];     // flat dims 128+2*lane, 128+2*lane+1
    int fe = 128 + 2*lane;
    float ylo = (fe < 128) ? x1 : x2;
    float yhi = ylo;
    w2 += bfus(pc & 0xffffu)*ylo + bfus(pc >> 16)*yhi;
    se0 += x0; se1 += x1; se2 += x2;
  }
  // stage: thread's w0,w1 -> flat dims 2*lane, 2*lane+1 ; w2 -> pair at 128+2*lane (sum of two dims!) BAD.
  // Use LDS per flat dim directly:
  __shared__ float acc[NVH];
  if (t < NVH) acc[t] = 0.f;
  __syncthreads();
  // each wave accumulated w0 (dim 2*lane), w1 (dim 2*lane+1), w2 pair combined -- need split; redo w2:
  // To keep correctness, recompute w2 split:
  float w2lo = 0.f, w2hi = 0.f;
  for (int n = gw; n < N; n += nw){
    const uint32* ep = emb + (size_t)n*96;
    float x2 = expf(scores[2*N + n] - m2);
    uint32 pc = ep[64+lane];
    w2lo += bfus(pc & 0xffffu)*x2;
    w2hi += bfus(pc >> 16)*x2;
  }
  atomicAdd(&acc[2*lane],       w0);
  atomicAdd(&acc[2*lane+1],     w1);
  if (lane < 32){
    atomicAdd(&acc[128+2*lane],   w2lo);
    atomicAdd(&acc[128+2*lane+1], w2hi);
  }
  __syncthreads();
  if (t < NVH) atomicAdd(&wsum[t], acc[t]);
  // scalar sums
  #pragma unroll
  for (int ofs = 32; ofs >= 1; ofs >>= 1){
    se0 += __shfl_xor(se0, ofs);
    se1 += __shfl_xor(se1, ofs);
    se2 += __shfl_xor(se2, ofs);
  }
  if (lane == 0){ shse[wv][0] = se0; shse[wv][1] = se1; shse[wv][2] = se2; }
  __syncthreads();
  if (t < 3){
    float s = shse[0][t] + shse[1][t] + shse[2][t] + shse[3][t];
    atomicAdd(&sumexp[t], s);
  }
  (void)shw;
}

// ---- view attention (tiny) ----
__global__ __launch_bounds__(64) void k_view(const float* __restrict__ wsum, const float* __restrict__ sumexp,
                                             const float* __restrict__ va_w1, const float* __restrict__ va_b1,
                                             const float* __restrict__ va_w2, const float* __restrict__ va_b2,
                                             float* __restrict__ g, float* __restrict__ out_vw, int N){
  __shared__ float avg[NV][64];
  __shared__ float z1[NV][32];
  int t = threadIdx.x;
  if (t < 64){
    for (int v = 0; v < NV; ++v) avg[v][t] = wsum[v*64+t] / (sumexp[v] * (float)N);
  }
  __syncthreads();
  if (t < 32){
    for (int v = 0; v < NV; ++v){
      float a = va_b1[t];
      for (int h = 0; h < 64; ++h) a += avg[v][h]*va_w1[h*32 + t];
      z1[v][t] = tanhf(a);
    }
  }
  __syncthreads();
  if (t == 0){
    float vs[NV];
    for (int v = 0; v < NV; ++v){
      float a = va_b2[0];
      for (int j = 0; j < 32; ++j) a += z1[v][j]*va_w2[j];
      vs[v] = a;
    }
    float m = fmaxf(vs[0], fmaxf(vs[1], vs[2]));
    float e0 = expf(vs[0]-m), e1 = expf(vs[1]-m), e2 = expf(vs[2]-m);
    float inv = 1.f/(e0+e1+e2);
    float vw0 = e0*inv, vw1 = e1*inv, vw2 = e2*inv;
    out_vw[0] = vw0; out_vw[1] = vw1; out_vw[2] = vw2;
    g[0] = vw0/sumexp[0]; g[1] = vw1/sumexp[1]; g[2] = vw2/sumexp[2];
  }
}

// ---- fused output + classifier + log_softmax (wave per node) ----
// emb [n][v][h] bf16: lane covers h = lane; views at dword offsets lane>>1 within v-blocks
__global__ __launch_bounds__(256) void k_fused(const uint32* __restrict__ emb, const float* __restrict__ scores,
                                               const unsigned* __restrict__ maxkey, const float* __restrict__ g,
                                               const float* __restrict__ cls_w, const float* __restrict__ cls_b,
                                               float* __restrict__ out, int N){
  int wid = (blockIdx.x*blockDim.x + threadIdx.x) >> 6;
  int lane = threadIdx.x & 63;
  if (wid >= N) return;
  int n = wid;
  float m0 = unkey(maxkey[0]), m1 = unkey(maxkey[1]), m2 = unkey(maxkey[2]);
  float w0 = expf(scores[n]       - m0)*g[0];
  float w1 = expf(scores[N + n]   - m1)*g[1];
  float w2 = expf(scores[2*N + n] - m2)*g[2];
  const uint32* ep = emb + (size_t)n*96;
  int dw = lane >> 1, hi = lane & 1;
  uint32 p0 = ep[dw];        // view 0, h-dims 2*dw(+1)
  uint32 p1 = ep[32 + dw];
  uint32 p2 = ep[64 + dw];
  float v0 = hi ? bfus(p0 >> 16) : bfus(p0 & 0xffffu);
  float v1 = hi ? bfus(p1 >> 16) : bfus(p1 & 0xffffu);
  float v2 = hi ? bfus(p2 >> 16) : bfus(p2 & 0xffffu);
  float fu = v0*w0 + v1*w1 + v2*w2;
  out[(size_t)2*N + (size_t)n*64 + lane] = fu;
  float c0 = fu*cls_w[lane*2 + 0];
  float c1 = fu*cls_w[lane*2 + 1];
  #pragma unroll
  for (int ofs = 32; ofs >= 1; ofs >>= 1){
    c0 += __shfl_xor(c0, ofs);
    c1 += __shfl_xor(c1, ofs);
  }
  if (lane == 0){
    float l0 = c0 + cls_b[0], l1 = c1 + cls_b[1];
    float m = fmaxf(l0, l1);
    float lse = m + logf(expf(l0-m) + expf(l1-m));
    out[(size_t)n*2]     = l0 - lse;
    out[(size_t)n*2 + 1] = l1 - lse;
  }
}

extern "C" void kernel_launch(void* const* d_in, const int* in_sizes, int n_in,
                              void* d_out, int out_size, void* d_ws, size_t ws_size,
                              hipStream_t stream){
  const float* x     = (const float*)d_in[0];
  const int*   ei    = (const int*)d_in[1];
  const float* Wv    = (const float*)d_in[2];
  const float* bv    = (const float*)d_in[3];
  const float* na_w  = (const float*)d_in[4];
  const float* na_b  = (const float*)d_in[5];
  const float* va_w1 = (const float*)d_in[6];
  const float* va_b1 = (const float*)d_in[7];
  const float* va_w2 = (const float*)d_in[8];
  const float* va_b2 = (const float*)d_in[9];
  const float* cls_w = (const float*)d_in[10];
  const float* cls_b = (const float*)d_in[11];
  int N = in_sizes[0] / (NV*DIMX);
  int E = in_sizes[1] / 2;
  float* out = (float*)d_out;
  int NT = (N + 15) / 16;

  char* wptr = (char*)d_ws;
  size_t off = 0;
  auto alloc = [&](size_t bytes){ void* p = wptr + off; off += (bytes + 255) & ~255ull; return p; };
  uchar*     hq       = (uchar*)alloc((size_t)N*192);         // v-major int8 table, 192B/node
  float*     scale4   = (float*)alloc((size_t)NT*4*4);
  uint32*    emb      = (uint32*)alloc((size_t)N*96*4);       // [n][v][h] bf16, 96 dwords/node
  int*       csr      = (int*)alloc((size_t)E*4);
  uint32*    ebuf     = (uint32*)alloc((size_t)E*4);
  int*       histT    = (int*)alloc((size_t)NBUK*NBLK*4);
  int*       rowstart = (int*)alloc((size_t)(N+1)*4);
  float*     dinv     = (float*)alloc((size_t)N*4);
  float*     scores   = (float*)alloc((size_t)3*N*4);
  unsigned*  maxkey   = (unsigned*)alloc(3*4);
  float*     sumexp   = (float*)alloc(3*4);
  float*     wsum     = (float*)alloc(192*4);
  float*     g        = (float*)alloc(3*4);
  uint32*    Wb       = (uint32*)alloc(3072*16);

  int EPB = (E + NBLK - 1) / NBLK;
  int nbuck = (N + 511) >> BSH;
  k_hist   <<<NBLK, 256, 0, stream>>>(ei, E, EPB, histT);
  k_hscan  <<<1, 1024, 0, stream>>>(histT);
  k_scatter<<<NBLK, 256, 0, stream>>>(ei, E, EPB, histT, ebuf);
  k_csr    <<<nbuck, 512, 0, stream>>>(ebuf, histT, E, N, rowstart, dinv, csr);
  k_wpack  <<<12, 256, 0, stream>>>(Wv, Wb, wsum, sumexp, maxkey);
  int hwaves = NT*3;
  k_h      <<<(hwaves*64+255)/256, 256, 0, stream>>>(x, Wb, dinv, hq, scale4, N, NT);
  k_aggv   <<<(N*64+255)/256, 256, 0, stream>>>((const uint32*)hq, scale4, rowstart, csr,
                                                dinv, bv, na_w, na_b, emb, scores, N);
  dim3 gm((N+2047)/2048, NV);
  k_max    <<<gm, 256, 0, stream>>>(scores, N, maxkey);
  k_wsum   <<<304, 256, 0, stream>>>(emb, scores, maxkey, wsum, sumexp, N);
  k_view   <<<1, 64, 0, stream>>>(wsum, sumexp, va_w1, va_b1, va_w2, va_b2, g,
                                  out + (size_t)2*N + (size_t)N*64, N);
  k_fused  <<<(N*64+255)/256, 256, 0, stream>>>(emb, scores, maxkey, g, cls_w, cls_b, out, N);
}

// Round 12
// 150.438 us; speedup vs baseline: 1.1270x; 1.1270x over previous
//
#include <hip/hip_runtime.h>
#include <math.h>

#define NV 3
#define DIMX 128
#define HD 64
#define NVH 192
#define NBLK 256     // edge-partition blocks for hist/scatter
#define NBUK 128     // dst buckets of 512 nodes
#define BSH 9        // log2(512)

typedef unsigned int uint32;
typedef unsigned short ushort16;
typedef unsigned char uchar;
typedef __attribute__((ext_vector_type(8))) short short8;
typedef __attribute__((ext_vector_type(4))) float f32x4;
typedef __attribute__((ext_vector_type(2))) unsigned int u32x2;

__device__ __forceinline__ unsigned fkey(float f){
  unsigned b = __float_as_uint(f);
  return (b & 0x80000000u) ? ~b : (b | 0x80000000u);
}
__device__ __forceinline__ float unkey(unsigned k){
  return __uint_as_float((k & 0x80000000u) ? (k ^ 0x80000000u) : ~k);
}
__device__ __forceinline__ uint32 bf16rne(float f){
  uint32 u = __float_as_uint(f);
  return (u + 0x7fffu + ((u >> 16) & 1u)) >> 16;
}
__device__ __forceinline__ float bfus(uint32 q){ return __uint_as_float(q << 16); }
__device__ __forceinline__ float ub0(uint32 p){ return (float)(p & 0xffu); }
__device__ __forceinline__ float ub1(uint32 p){ return (float)((p >> 8) & 0xffu); }
__device__ __forceinline__ float ub2(uint32 p){ return (float)((p >> 16) & 0xffu); }
__device__ __forceinline__ float ub3(uint32 p){ return (float)(p >> 24); }

// ---- CSR build: two-level counting sort, LDS atomics only ----
__global__ __launch_bounds__(256) void k_hist(const int* __restrict__ ei, int E, int EPB,
                                              int* __restrict__ histT){
  __shared__ int sh[NBUK];
  int t = threadIdx.x, b = blockIdx.x;
  if (t < NBUK) sh[t] = 0;
  __syncthreads();
  int e0 = b*EPB, e1 = min(e0 + EPB, E);
  for (int i = e0 + t; i < e1; i += 256){
    int d = ei[E + i];
    atomicAdd(&sh[d >> BSH], 1);
  }
  __syncthreads();
  if (t < NBUK) histT[t*NBLK + b] = sh[t];
}

__global__ __launch_bounds__(1024) void k_hscan(int* __restrict__ histT){
  __shared__ int sh[1024];
  int t = threadIdx.x;
  int lo = t*32;
  int vals[32]; int s = 0;
  #pragma unroll
  for (int k = 0; k < 32; ++k){ vals[k] = histT[lo+k]; s += vals[k]; }
  sh[t] = s; __syncthreads();
  for (int ofs = 1; ofs < 1024; ofs <<= 1){
    int v = (t >= ofs) ? sh[t-ofs] : 0;
    __syncthreads();
    sh[t] += v;
    __syncthreads();
  }
  int run = sh[t] - s;
  #pragma unroll
  for (int k = 0; k < 32; ++k){ histT[lo+k] = run; run += vals[k]; }
}

// pack edge as (dst_local<<16)|src  (valid: src < 65536, dst_local < 512)
__global__ __launch_bounds__(256) void k_scatter(const int* __restrict__ ei, int E, int EPB,
                                                 const int* __restrict__ ofsT, uint32* __restrict__ ebuf){
  __shared__ int cur[NBUK];
  int t = threadIdx.x, b = blockIdx.x;
  if (t < NBUK) cur[t] = ofsT[t*NBLK + b];
  __syncthreads();
  int e0 = b*EPB, e1 = min(e0 + EPB, E);
  for (int i = e0 + t; i < e1; i += 256){
    int s = ei[i], d = ei[E + i];
    int pos = atomicAdd(&cur[d >> BSH], 1);
    ebuf[pos] = ((uint32)(d & 511) << 16) | (uint32)s;
  }
}

__global__ __launch_bounds__(512) void k_csr(const uint32* __restrict__ ebuf, const int* __restrict__ ofsT,
                                             int E, int N, int* __restrict__ rowstart,
                                             float* __restrict__ dinv, int* __restrict__ csr){
  __shared__ int cnt[512];
  __shared__ int pre[512];
  int t = threadIdx.x, b = blockIdx.x;
  int estart = ofsT[b*NBLK];
  int eend   = ((b+1)*NBLK < NBUK*NBLK) ? ofsT[(b+1)*NBLK] : E;
  int n0 = b << BSH;
  int nn = min(512, N - n0);
  cnt[t] = 0;
  __syncthreads();
  for (int i = estart + t; i < eend; i += 512){
    atomicAdd(&cnt[ebuf[i] >> 16], 1);
  }
  __syncthreads();
  int c = cnt[t];
  pre[t] = c;
  __syncthreads();
  for (int ofs = 1; ofs < 512; ofs <<= 1){
    int v = (t >= ofs) ? pre[t-ofs] : 0;
    __syncthreads();
    pre[t] += v;
    __syncthreads();
  }
  int excl = pre[t] - c;
  if (t < nn){
    rowstart[n0 + t] = estart + excl;
    dinv[n0 + t] = rsqrtf((float)(c + 1));
  }
  if (b == gridDim.x - 1 && t == 0) rowstart[N] = E;
  cnt[t] = estart + excl;
  __syncthreads();
  for (int i = estart + t; i < eend; i += 512){
    uint32 e = ebuf[i];
    int pos = atomicAdd(&cnt[e >> 16], 1);
    csr[pos] = (int)(e & 0xFFFFu);
  }
}

// ---- pack Wv into per-lane MFMA B-fragment order; block 0 also zeroes accumulators ----
__global__ __launch_bounds__(256) void k_wpack(const float* __restrict__ Wv, uint32* __restrict__ Wb,
                                               float* __restrict__ wsum, float* __restrict__ sumexp,
                                               unsigned* __restrict__ maxkey){
  int t = blockIdx.x*blockDim.x + threadIdx.x;
  if (blockIdx.x == 0){
    int u = threadIdx.x;
    if (u < NVH) wsum[u] = 0.f;
    else if (u < NVH+3) sumexp[u-NVH] = 0.f;
    else if (u < NVH+6) maxkey[u-NVH-3] = 0u;
  }
  if (t >= 3072) return;
  int l = t & 63, s = (t >> 6) & 3, c = (t >> 8) & 3, v = t >> 10;
  int h = c*16 + (l & 15);
  int kbase = s*32 + (l >> 4)*8;
  const float* wp = Wv + v*8192 + h;
  uint32 o[4];
  #pragma unroll
  for (int jj = 0; jj < 4; ++jj){
    uint32 lo = bf16rne(wp[(kbase + 2*jj    )*64]);
    uint32 hi = bf16rne(wp[(kbase + 2*jj + 1)*64]);
    o[jj] = lo | (hi << 16);
  }
  Wb[t*4+0] = o[0]; Wb[t*4+1] = o[1]; Wb[t*4+2] = o[2]; Wb[t*4+3] = o[3];
}

// ---- MFMA linear transform, one wave per (16-node tile, view), fused int8 quant ----
// v-major packed table: hq8[n*192 + v*64 + h] = uint8(q+128); 48 dwords/node
// per-(tile,view) scale in scale4[tile*4 + v]
__global__ __launch_bounds__(256) void k_h(const float* __restrict__ x, const uint32* __restrict__ Wb,
                                           const float* __restrict__ dinv,
                                           uchar* __restrict__ hq8, float* __restrict__ scale4,
                                           int N, int NT){
  int wv = (blockIdx.x*blockDim.x + threadIdx.x) >> 6;
  int lane = threadIdx.x & 63;
  int tile = wv / 3;
  int v = wv - tile*3;
  if (tile >= NT) return;
  int jrow = lane & 15;
  int kq   = lane >> 4;
  int nrow = tile*16 + jrow;
  const float* xr = x + (size_t)nrow*384 + v*128 + kq*8;
  const short8* WB = (const short8*)Wb;

  f32x4 acc[4] = {};
  #pragma unroll
  for (int s = 0; s < 4; ++s){
    const float* p = xr + s*32;
    float4 f = *(const float4*)p, g = *(const float4*)(p+4);
    short8 a;
    a[0]=(short)bf16rne(f.x); a[1]=(short)bf16rne(f.y); a[2]=(short)bf16rne(f.z); a[3]=(short)bf16rne(f.w);
    a[4]=(short)bf16rne(g.x); a[5]=(short)bf16rne(g.y); a[6]=(short)bf16rne(g.z); a[7]=(short)bf16rne(g.w);
    #pragma unroll
    for (int c = 0; c < 4; ++c){
      short8 b = WB[(v*4 + c)*256 + s*64 + lane];
      acc[c] = __builtin_amdgcn_mfma_f32_16x16x32_bf16(a, b, acc[c], 0, 0, 0);
    }
  }

  float vv[4][4];
  float mx = 0.f;
  #pragma unroll
  for (int r = 0; r < 4; ++r){
    int n = tile*16 + kq*4 + r;
    float dv = dinv[n];
    #pragma unroll
    for (int c = 0; c < 4; ++c){
      float t = acc[c][r]*dv;
      vv[c][r] = t;
      mx = fmaxf(mx, fabsf(t));
    }
  }
  #pragma unroll
  for (int ofs = 1; ofs < 64; ofs <<= 1) mx = fmaxf(mx, __shfl_xor(mx, ofs));
  float inv = (mx > 0.f) ? 127.0f/mx : 0.f;
  #pragma unroll
  for (int r = 0; r < 4; ++r){
    int n = tile*16 + kq*4 + r;
    #pragma unroll
    for (int c = 0; c < 4; ++c){
      uint32 q = (uint32)(int)(vv[c][r]*inv + 128.5f);
      hq8[(size_t)n*192 + v*64 + c*16 + jrow] = (uchar)q;
    }
  }
  if (lane == 0) scale4[tile*4 + v] = mx * (1.0f/127.0f);
}

// ---- fused 3-view aggregation: 1 aligned dword gather + 1 scalar scale per edge ----
// lane j<48: view v=j>>4, h-dims 4*(j&15)..+3 (dword j of the 48-dword node record)
__global__ __launch_bounds__(256) void k_aggv(const uint32* __restrict__ hq4, const float* __restrict__ sc,
                                              const int* __restrict__ rowstart, const int* __restrict__ csr,
                                              const float* __restrict__ dinv, const float* __restrict__ bv,
                                              const float* __restrict__ na_w, const float* __restrict__ na_b,
                                              uint32* __restrict__ emb, float* __restrict__ scores, int N){
  int wid = (blockIdx.x*blockDim.x + threadIdx.x) >> 6;
  int lane = threadIdx.x & 63;
  if (wid >= N) return;
  int n = wid;
  int jl = (lane < 48) ? lane : 0;
  int v = jl >> 4;
  // self-loop
  uint32 ps = hq4[(size_t)n*48 + jl];
  float cs = sc[((n >> 4) << 2) + v];
  float a0 = cs*ub0(ps), a1 = cs*ub1(ps), a2 = cs*ub2(ps), a3 = cs*ub3(ps);
  float ssum = cs;
  int r0 = rowstart[n], r1 = rowstart[n+1];
  for (int base = r0; base < r1; base += 64){
    int m = r1 - base; if (m > 64) m = 64;
    int sv = (lane < m) ? __builtin_nontemporal_load(&csr[base + lane]) : 0;
    int i = 0;
    for (; i + 3 < m; i += 4){
      int s0 = __shfl(sv, i), s1 = __shfl(sv, i+1), s2 = __shfl(sv, i+2), s3 = __shfl(sv, i+3);
      uint32 p0 = hq4[(size_t)s0*48 + jl];
      uint32 p1 = hq4[(size_t)s1*48 + jl];
      uint32 p2 = hq4[(size_t)s2*48 + jl];
      uint32 p3 = hq4[(size_t)s3*48 + jl];
      float f0 = sc[((s0 >> 4) << 2) + v];
      float f1 = sc[((s1 >> 4) << 2) + v];
      float f2 = sc[((s2 >> 4) << 2) + v];
      float f3 = sc[((s3 >> 4) << 2) + v];
      a0 = fmaf(f0, ub0(p0), a0); a1 = fmaf(f0, ub1(p0), a1); a2 = fmaf(f0, ub2(p0), a2); a3 = fmaf(f0, ub3(p0), a3);
      a0 = fmaf(f1, ub0(p1), a0); a1 = fmaf(f1, ub1(p1), a1); a2 = fmaf(f1, ub2(p1), a2); a3 = fmaf(f1, ub3(p1), a3);
      a0 = fmaf(f2, ub0(p2), a0); a1 = fmaf(f2, ub1(p2), a1); a2 = fmaf(f2, ub2(p2), a2); a3 = fmaf(f2, ub3(p2), a3);
      a0 = fmaf(f3, ub0(p3), a0); a1 = fmaf(f3, ub1(p3), a1); a2 = fmaf(f3, ub2(p3), a2); a3 = fmaf(f3, ub3(p3), a3);
      ssum += f0 + f1 + f2 + f3;
    }
    for (; i < m; ++i){
      int s = __shfl(sv, i);
      uint32 p = hq4[(size_t)s*48 + jl];
      float f = sc[((s >> 4) << 2) + v];
      a0 = fmaf(f, ub0(p), a0); a1 = fmaf(f, ub1(p), a1); a2 = fmaf(f, ub2(p), a2); a3 = fmaf(f, ub3(p), a3);
      ssum += f;
    }
  }
  float off128 = 128.0f*ssum;
  a0 -= off128; a1 -= off128; a2 -= off128; a3 -= off128;
  float dv = dinv[n];
  float4 bb = *(const float4*)&bv[jl*4];
  float e0 = fmaxf(a0*dv + bb.x, 0.f);
  float e1 = fmaxf(a1*dv + bb.y, 0.f);
  float e2 = fmaxf(a2*dv + bb.z, 0.f);
  float e3 = fmaxf(a3*dv + bb.w, 0.f);
  if (lane < 48){
    u32x2 pk;
    pk.x = bf16rne(e0) | (bf16rne(e1) << 16);
    pk.y = bf16rne(e2) | (bf16rne(e3) << 16);
    __builtin_nontemporal_store(pk, (u32x2*)(emb + (size_t)n*96 + 2*jl));
  }
  float4 nw = *(const float4*)&na_w[(jl & 15)*4];
  float s = e0*nw.x + e1*nw.y + e2*nw.z + e3*nw.w;
  s += __shfl_xor(s, 1);
  s += __shfl_xor(s, 2);
  s += __shfl_xor(s, 4);
  s += __shfl_xor(s, 8);
  if (lane < 48 && (lane & 15) == 0) scores[(size_t)v*N + n] = s + na_b[0];
}

// ---- global max per view ----
__global__ void k_max(const float* __restrict__ scores, int N, unsigned* __restrict__ maxkey){
  __shared__ float sh[256];
  int v = blockIdx.y;
  const float* sp = scores + (size_t)v*N;
  int base = blockIdx.x*2048 + threadIdx.x;
  float m = -3.0e38f;
  #pragma unroll
  for (int k = 0; k < 8; ++k){
    int i = base + k*256;
    if (i < N) m = fmaxf(m, sp[i]);
  }
  sh[threadIdx.x] = m; __syncthreads();
  for (int ofs = 128; ofs >= 1; ofs >>= 1){
    if (threadIdx.x < ofs) sh[threadIdx.x] = fmaxf(sh[threadIdx.x], sh[threadIdx.x+ofs]);
    __syncthreads();
  }
  if (threadIdx.x == 0) atomicMax(&maxkey[v], fkey(sh[0]));
}

// ---- sum(exp) per view + weighted sum over nodes, single pass ----
// emb: [n][v][h] bf16 pairs, dword (n*96 + v*32 + k) = h-dims (2k, 2k+1) of view v
// lane reads dword `lane` (flat dims 2*lane, 2*lane+1; weight x0 for lane<32, x1 else)
// and dword 64+(lane&31) (view 2; lanes<32 stage it)
__global__ __launch_bounds__(256) void k_wsum(const uint32* __restrict__ emb, const float* __restrict__ scores,
                                              const unsigned* __restrict__ maxkey, float* __restrict__ wsum,
                                              float* __restrict__ sumexp, int N){
  __shared__ float shw[4][NVH];
  __shared__ float shse[4][4];
  int t = threadIdx.x;
  int lane = t & 63;
  int wv = t >> 6;
  int gw = (blockIdx.x*blockDim.x + t) >> 6;
  int nw = (gridDim.x*blockDim.x) >> 6;
  int l32 = lane & 31;
  float m0 = unkey(maxkey[0]), m1 = unkey(maxkey[1]), m2 = unkey(maxkey[2]);
  float wa_lo=0.f, wa_hi=0.f, wb_lo=0.f, wb_hi=0.f;
  float se0=0.f, se1=0.f, se2=0.f;
  bool isv1 = lane >= 32;
  for (int n = gw; n < N; n += nw){
    const uint32* ep = emb + (size_t)n*96;
    float x0 = expf(scores[n]       - m0);
    float x1 = expf(scores[N + n]   - m1);
    float x2 = expf(scores[2*N + n] - m2);
    uint32 pa = ep[lane];
    uint32 pb = ep[64 + l32];
    float xa = isv1 ? x1 : x0;
    wa_lo += bfus(pa & 0xffffu)*xa;
    wa_hi += bfus(pa >> 16)*xa;
    wb_lo += bfus(pb & 0xffffu)*x2;
    wb_hi += bfus(pb >> 16)*x2;
    se0 += x0; se1 += x1; se2 += x2;
  }
  shw[wv][2*lane]   = wa_lo;     // flat dim 2*lane covers views 0,1 exactly
  shw[wv][2*lane+1] = wa_hi;
  __syncthreads();               // (shw[wv][128..191] written below by lanes<32)
  if (lane < 32){
    shw[wv][128 + 2*lane]   = wb_lo;
    shw[wv][128 + 2*lane+1] = wb_hi;
  }
  #pragma unroll
  for (int ofs = 32; ofs >= 1; ofs >>= 1){
    se0 += __shfl_xor(se0, ofs);
    se1 += __shfl_xor(se1, ofs);
    se2 += __shfl_xor(se2, ofs);
  }
  if (lane == 0){ shse[wv][0] = se0; shse[wv][1] = se1; shse[wv][2] = se2; }
  __syncthreads();
  if (t < NVH){
    float s = shw[0][t] + shw[1][t] + shw[2][t] + shw[3][t];
    atomicAdd(&wsum[t], s);
  } else if (t >= NVH && t < NVH+3){
    int v = t - NVH;
    float s = shse[0][v] + shse[1][v] + shse[2][v] + shse[3][v];
    atomicAdd(&sumexp[v], s);
  }
}

// ---- view attention (tiny) ----
__global__ __launch_bounds__(64) void k_view(const float* __restrict__ wsum, const float* __restrict__ sumexp,
                                             const float* __restrict__ va_w1, const float* __restrict__ va_b1,
                                             const float* __restrict__ va_w2, const float* __restrict__ va_b2,
                                             float* __restrict__ g, float* __restrict__ out_vw, int N){
  __shared__ float avg[NV][64];
  __shared__ float z1[NV][32];
  int t = threadIdx.x;
  if (t < 64){
    for (int v = 0; v < NV; ++v) avg[v][t] = wsum[v*64+t] / (sumexp[v] * (float)N);
  }
  __syncthreads();
  if (t < 32){
    for (int v = 0; v < NV; ++v){
      float a = va_b1[t];
      for (int h = 0; h < 64; ++h) a += avg[v][h]*va_w1[h*32 + t];
      z1[v][t] = tanhf(a);
    }
  }
  __syncthreads();
  if (t == 0){
    float vs[NV];
    for (int v = 0; v < NV; ++v){
      float a = va_b2[0];
      for (int j = 0; j < 32; ++j) a += z1[v][j]*va_w2[j];
      vs[v] = a;
    }
    float m = fmaxf(vs[0], fmaxf(vs[1], vs[2]));
    float e0 = expf(vs[0]-m), e1 = expf(vs[1]-m), e2 = expf(vs[2]-m);
    float inv = 1.f/(e0+e1+e2);
    float vw0 = e0*inv, vw1 = e1*inv, vw2 = e2*inv;
    out_vw[0] = vw0; out_vw[1] = vw1; out_vw[2] = vw2;
    g[0] = vw0/sumexp[0]; g[1] = vw1/sumexp[1]; g[2] = vw2/sumexp[2];
  }
}

// ---- fused output + classifier + log_softmax (wave per node) ----
// emb [n][v][h] bf16: dword (v*32 + (lane>>1)), half = lane&1 → h = lane
__global__ __launch_bounds__(256) void k_fused(const uint32* __restrict__ emb, const float* __restrict__ scores,
                                               const unsigned* __restrict__ maxkey, const float* __restrict__ g,
                                               const float* __restrict__ cls_w, const float* __restrict__ cls_b,
                                               float* __restrict__ out, int N){
  int wid = (blockIdx.x*blockDim.x + threadIdx.x) >> 6;
  int lane = threadIdx.x & 63;
  if (wid >= N) return;
  int n = wid;
  float m0 = unkey(maxkey[0]), m1 = unkey(maxkey[1]), m2 = unkey(maxkey[2]);
  float w0 = expf(scores[n]       - m0)*g[0];
  float w1 = expf(scores[N + n]   - m1)*g[1];
  float w2 = expf(scores[2*N + n] - m2)*g[2];
  const uint32* ep = emb + (size_t)n*96;
  int dw = lane >> 1, hi = lane & 1;
  uint32 p0 = ep[dw];
  uint32 p1 = ep[32 + dw];
  uint32 p2 = ep[64 + dw];
  float v0 = hi ? bfus(p0 >> 16) : bfus(p0 & 0xffffu);
  float v1 = hi ? bfus(p1 >> 16) : bfus(p1 & 0xffffu);
  float v2 = hi ? bfus(p2 >> 16) : bfus(p2 & 0xffffu);
  float fu = v0*w0 + v1*w1 + v2*w2;
  out[(size_t)2*N + (size_t)n*64 + lane] = fu;
  float c0 = fu*cls_w[lane*2 + 0];
  float c1 = fu*cls_w[lane*2 + 1];
  #pragma unroll
  for (int ofs = 32; ofs >= 1; ofs >>= 1){
    c0 += __shfl_xor(c0, ofs);
    c1 += __shfl_xor(c1, ofs);
  }
  if (lane == 0){
    float l0 = c0 + cls_b[0], l1 = c1 + cls_b[1];
    float m = fmaxf(l0, l1);
    float lse = m + logf(expf(l0-m) + expf(l1-m));
    out[(size_t)n*2]     = l0 - lse;
    out[(size_t)n*2 + 1] = l1 - lse;
  }
}

extern "C" void kernel_launch(void* const* d_in, const int* in_sizes, int n_in,
                              void* d_out, int out_size, void* d_ws, size_t ws_size,
                              hipStream_t stream){
  const float* x     = (const float*)d_in[0];
  const int*   ei    = (const int*)d_in[1];
  const float* Wv    = (const float*)d_in[2];
  const float* bv    = (const float*)d_in[3];
  const float* na_w  = (const float*)d_in[4];
  const float* na_b  = (const float*)d_in[5];
  const float* va_w1 = (const float*)d_in[6];
  const float* va_b1 = (const float*)d_in[7];
  const float* va_w2 = (const float*)d_in[8];
  const float* va_b2 = (const float*)d_in[9];
  const float* cls_w = (const float*)d_in[10];
  const float* cls_b = (const float*)d_in[11];
  int N = in_sizes[0] / (NV*DIMX);
  int E = in_sizes[1] / 2;
  float* out = (float*)d_out;
  int NT = (N + 15) / 16;

  char* wptr = (char*)d_ws;
  size_t off = 0;
  auto alloc = [&](size_t bytes){ void* p = wptr + off; off += (bytes + 255) & ~255ull; return p; };
  uchar*     hq       = (uchar*)alloc((size_t)N*192);         // v-major int8 table, 192B/node
  float*     scale4   = (float*)alloc((size_t)NT*4*4);
  uint32*    emb      = (uint32*)alloc((size_t)N*96*4);       // [n][v][h] bf16, 96 dwords/node
  int*       csr      = (int*)alloc((size_t)E*4);
  uint32*    ebuf     = (uint32*)alloc((size_t)E*4);
  int*       histT    = (int*)alloc((size_t)NBUK*NBLK*4);
  int*       rowstart = (int*)alloc((size_t)(N+1)*4);
  float*     dinv     = (float*)alloc((size_t)N*4);
  float*     scores   = (float*)alloc((size_t)3*N*4);
  unsigned*  maxkey   = (unsigned*)alloc(3*4);
  float*     sumexp   = (float*)alloc(3*4);
  float*     wsum     = (float*)alloc(192*4);
  float*     g        = (float*)alloc(3*4);
  uint32*    Wb       = (uint32*)alloc(3072*16);

  int EPB = (E + NBLK - 1) / NBLK;
  int nbuck = (N + 511) >> BSH;
  k_hist   <<<NBLK, 256, 0, stream>>>(ei, E, EPB, histT);
  k_hscan  <<<1, 1024, 0, stream>>>(histT);
  k_scatter<<<NBLK, 256, 0, stream>>>(ei, E, EPB, histT, ebuf);
  k_csr    <<<nbuck, 512, 0, stream>>>(ebuf, histT, E, N, rowstart, dinv, csr);
  k_wpack  <<<12, 256, 0, stream>>>(Wv, Wb, wsum, sumexp, maxkey);
  int hwaves = NT*3;
  k_h      <<<(hwaves*64+255)/256, 256, 0, stream>>>(x, Wb, dinv, hq, scale4, N, NT);
  k_aggv   <<<(N*64+255)/256, 256, 0, stream>>>((const uint32*)hq, scale4, rowstart, csr,
                                                dinv, bv, na_w, na_b, emb, scores, N);
  dim3 gm((N+2047)/2048, NV);
  k_max    <<<gm, 256, 0, stream>>>(scores, N, maxkey);
  k_wsum   <<<608, 256, 0, stream>>>(emb, scores, maxkey, wsum, sumexp, N);
  k_view   <<<1, 64, 0, stream>>>(wsum, sumexp, va_w1, va_b1, va_w2, va_b2, g,
                                  out + (size_t)2*N + (size_t)N*64, N);
  k_fused  <<<(N*64+255)/256, 256, 0, stream>>>(emb, scores, maxkey, g, cls_w, cls_b, out, N);
}